// Round 1
// baseline (491.897 us; speedup 1.0000x reference)
//
#include <hip/hip_runtime.h>
#include <hip/hip_bf16.h>

// Problem constants (from reference)
#define MM 5000      // matches
#define LC 4800      // coarse cells
#define NCH 128      // C_F
// feat_f: [4][128][240][320], feat_c: [4][4800][256]

typedef __attribute__((ext_vector_type(8))) short bf16x8;
typedef __attribute__((ext_vector_type(4))) float f32x4;

__device__ __forceinline__ unsigned short f2bf(float f) {
    unsigned int u = __builtin_bit_cast(unsigned int, f);
    u += 0x7fffu + ((u >> 16) & 1u);   // RNE
    return (unsigned short)(u >> 16);
}

// K0: Wcomb = merge_w[:,128:] @ down_proj_w  -> bf16 [128][256]
//     W1    = merge_w[:,:128]                -> bf16 [128][128]
//     bvec  = merge_b + down_proj_b @ merge_w[:,128:].T   (fp32 [128])
__global__ void k0_prep(const float* __restrict__ merge_w,
                        const float* __restrict__ down_w,
                        const float* __restrict__ merge_b,
                        const float* __restrict__ down_b,
                        unsigned short* __restrict__ w1_bf,
                        unsigned short* __restrict__ wc_bf,
                        float* __restrict__ bvec)
{
    int o = blockIdx.x * 256 + threadIdx.x;        // 128 blocks -> o in [0,32768)
    int cf = o >> 8, cc = o & 255;
    const float* w2row = merge_w + cf * 256 + 128; // W2[cf][:]
    float acc = 0.f;
    #pragma unroll 4
    for (int j = 0; j < 128; ++j)
        acc = fmaf(w2row[j], down_w[j * 256 + cc], acc);
    wc_bf[o] = f2bf(acc);
    if (o < 16384)
        w1_bf[o] = f2bf(merge_w[(o >> 7) * 256 + (o & 127)]);
    if (o < 128) {
        const float* w2r = merge_w + o * 256 + 128;
        float a = merge_b[o];
        for (int j = 0; j < 128; ++j) a = fmaf(down_b[j], w2r[j], a);
        bvec[o] = a;
    }
}

// K1: bias2[sm][cf] = feat_c_row(sm) @ Wcomb[cf][:] + bvec[cf]; sm in [0,10000)
// block = 32 sm rows x 128 cf, K=256, bf16 MFMA 16x16x32
__global__ void __launch_bounds__(256) k1_bias(
    const float* __restrict__ feat_c0, const float* __restrict__ feat_c1,
    const int* __restrict__ b_ids, const int* __restrict__ i_ids,
    const int* __restrict__ j_ids,
    const unsigned short* __restrict__ wc_bf, const float* __restrict__ bvec,
    float* __restrict__ bias2)
{
    __shared__ unsigned short ac[32][264];   // 256 + 8 pad (bank shift)
    const int t = threadIdx.x;
    const int base = blockIdx.x * 32;
    {
        int row = t >> 3;
        int seg = (t & 7) * 32;
        int sm = base + row; if (sm > 2 * MM - 1) sm = 2 * MM - 1;
        int side = sm >= MM;
        int mm = sm - side * MM;
        int id = side ? j_ids[mm] : i_ids[mm];
        int b  = b_ids[mm];
        const float* src = (side ? feat_c1 : feat_c0)
                           + (size_t)(b * LC + id) * 256 + seg;
        const float4* s4 = (const float4*)src;
        #pragma unroll
        for (int i = 0; i < 8; ++i) {
            float4 v = s4[i];
            ushort4 u; u.x = f2bf(v.x); u.y = f2bf(v.y); u.z = f2bf(v.z); u.w = f2bf(v.w);
            *(ushort4*)&ac[row][seg + i * 4] = u;
        }
    }
    __syncthreads();
    const int lane = t & 63, wave = t >> 6;
    const int ln = lane & 15, q = lane >> 4;
    const int n0 = wave * 32;
    f32x4 acc[2][2] = {};
    #pragma unroll
    for (int k0 = 0; k0 < 8; ++k0) {
        bf16x8 a0 = *(const bf16x8*)&ac[ln][k0 * 32 + q * 8];
        bf16x8 a1 = *(const bf16x8*)&ac[16 + ln][k0 * 32 + q * 8];
        bf16x8 b0 = *(const bf16x8*)(wc_bf + (size_t)(n0 + ln) * 256 + k0 * 32 + q * 8);
        bf16x8 b1 = *(const bf16x8*)(wc_bf + (size_t)(n0 + 16 + ln) * 256 + k0 * 32 + q * 8);
        acc[0][0] = __builtin_amdgcn_mfma_f32_16x16x32_bf16(a0, b0, acc[0][0], 0, 0, 0);
        acc[0][1] = __builtin_amdgcn_mfma_f32_16x16x32_bf16(a0, b1, acc[0][1], 0, 0, 0);
        acc[1][0] = __builtin_amdgcn_mfma_f32_16x16x32_bf16(a1, b0, acc[1][0], 0, 0, 0);
        acc[1][1] = __builtin_amdgcn_mfma_f32_16x16x32_bf16(a1, b1, acc[1][1], 0, 0, 0);
    }
    #pragma unroll
    for (int mt = 0; mt < 2; ++mt)
      #pragma unroll
      for (int nt = 0; nt < 2; ++nt) {
        int cf = n0 + nt * 16 + ln;
        float bv = bvec[cf];
        #pragma unroll
        for (int r = 0; r < 4; ++r) {
            int sm = base + mt * 16 + q * 4 + r;
            if (sm < 2 * MM)
                bias2[(size_t)sm * 128 + cf] = acc[mt][nt][r] + bv;
        }
      }
}

// K2: per match-side: gather scrambled-view window [25][128] -> LDS bf16,
// D = fw @ W1^T + bias2 row, store [25][128] fp32.
__global__ void __launch_bounds__(256) k2_main(
    const float* __restrict__ feat_f0, const float* __restrict__ feat_f1,
    const int* __restrict__ b_ids, const int* __restrict__ i_ids,
    const int* __restrict__ j_ids,
    const unsigned short* __restrict__ w1_bf, const float* __restrict__ bias2,
    float* __restrict__ out)
{
    __shared__ unsigned short fw[32][136];    // 25 used rows; +8 pad
    __shared__ unsigned short w1[128][136];
    __shared__ float brow[128];
    const int t = threadIdx.x;
    const int bx = blockIdx.x;                 // [0,10000)
    const int side = bx >= MM;
    const int m = bx - side * MM;
    const float* feat = side ? feat_f1 : feat_f0;
    const int l = side ? j_ids[m] : i_ids[m];
    const int n = b_ids[m];

    // stage W1 (bf16 [128][128]) into LDS
    {
        int row = t >> 1, seg = (t & 1) * 64;
        const uint4* s = (const uint4*)(w1_bf + row * 128 + seg);
        #pragma unroll
        for (int i = 0; i < 8; ++i)
            *(uint4*)&w1[row][seg + i * 8] = s[i];
    }
    if (t < 128) brow[t] = bias2[(size_t)bx * 128 + t];

    // gather: view element (l, w, c) = unfold flat l*3200 + w*128 + c
    const int fbase = l * 3200;
    const float* fn = feat + (size_t)n * (128 * 240 * 320);
    #pragma unroll
    for (int it = 0; it < 13; ++it) {
        int idx = t + it * 256;
        if (idx < 3200) {
            int F  = fbase + idx;
            int cc = F / 4800;  int p  = F - cc * 4800;
            int ch = cc / 25;   int k5 = cc - ch * 25;
            int kh = k5 / 5;    int kw = k5 - kh * 5;
            int ho = p / 80;    int wo = p - ho * 80;
            int r   = 4 * ho + kh - 2;      // always < 240
            int col = 4 * wo + kw - 2;      // always < 320
            float v = 0.f;
            if (r >= 0 && col >= 0)
                v = fn[(ch * 240 + r) * 320 + col];
            fw[idx >> 7][idx & 127] = f2bf(v);
        }
    }
    __syncthreads();

    const int lane = t & 63, wave = t >> 6;
    const int ln = lane & 15, q = lane >> 4;
    const int n0 = wave * 32;
    f32x4 acc[2][2] = {};
    #pragma unroll
    for (int k0 = 0; k0 < 4; ++k0) {
        bf16x8 a0 = *(const bf16x8*)&fw[ln][k0 * 32 + q * 8];
        bf16x8 a1 = *(const bf16x8*)&fw[16 + ln][k0 * 32 + q * 8];   // rows>=25 garbage: only feeds D rows>=25 (unstored)
        bf16x8 b0 = *(const bf16x8*)&w1[n0 + ln][k0 * 32 + q * 8];
        bf16x8 b1 = *(const bf16x8*)&w1[n0 + 16 + ln][k0 * 32 + q * 8];
        acc[0][0] = __builtin_amdgcn_mfma_f32_16x16x32_bf16(a0, b0, acc[0][0], 0, 0, 0);
        acc[0][1] = __builtin_amdgcn_mfma_f32_16x16x32_bf16(a0, b1, acc[0][1], 0, 0, 0);
        acc[1][0] = __builtin_amdgcn_mfma_f32_16x16x32_bf16(a1, b0, acc[1][0], 0, 0, 0);
        acc[1][1] = __builtin_amdgcn_mfma_f32_16x16x32_bf16(a1, b1, acc[1][1], 0, 0, 0);
    }
    float* ob = out + (size_t)bx * 3200;
    #pragma unroll
    for (int nt = 0; nt < 2; ++nt) {
        int cf = n0 + nt * 16 + ln;
        float bv = brow[cf];
        #pragma unroll
        for (int mt = 0; mt < 2; ++mt)
          #pragma unroll
          for (int r = 0; r < 4; ++r) {
            int w = mt * 16 + q * 4 + r;
            if (w < 25)
                ob[w * 128 + cf] = acc[mt][nt][r] + bv;
          }
    }
}

extern "C" void kernel_launch(void* const* d_in, const int* in_sizes, int n_in,
                              void* d_out, int out_size, void* d_ws, size_t ws_size,
                              hipStream_t stream) {
    const float* feat_f0 = (const float*)d_in[0];
    const float* feat_f1 = (const float*)d_in[1];
    const float* feat_c0 = (const float*)d_in[2];
    const float* feat_c1 = (const float*)d_in[3];
    const int*   b_ids   = (const int*)d_in[4];
    const int*   i_ids   = (const int*)d_in[5];
    const int*   j_ids   = (const int*)d_in[6];
    const float* down_w  = (const float*)d_in[7];
    const float* down_b  = (const float*)d_in[8];
    const float* merge_w = (const float*)d_in[9];
    const float* merge_b = (const float*)d_in[10];
    float* out = (float*)d_out;

    char* ws = (char*)d_ws;
    unsigned short* w1_bf = (unsigned short*)(ws);            // 32 KB
    unsigned short* wc_bf = (unsigned short*)(ws + 32768);    // 64 KB
    float* bvec  = (float*)(ws + 98304);                      // 512 B
    float* bias2 = (float*)(ws + 98816);                      // 10000*128*4 = 5.12 MB

    hipLaunchKernelGGL(k0_prep, dim3(128), dim3(256), 0, stream,
                       merge_w, down_w, merge_b, down_b, w1_bf, wc_bf, bvec);
    hipLaunchKernelGGL(k1_bias, dim3((2 * MM + 31) / 32), dim3(256), 0, stream,
                       feat_c0, feat_c1, b_ids, i_ids, j_ids, wc_bf, bvec, bias2);
    hipLaunchKernelGGL(k2_main, dim3(2 * MM), dim3(256), 0, stream,
                       feat_f0, feat_f1, b_ids, i_ids, j_ids, w1_bf, bias2, out);
}

// Round 2
// 440.674 us; speedup vs baseline: 1.1162x; 1.1162x over previous
//
#include <hip/hip_runtime.h>
#include <hip/hip_bf16.h>

// Problem constants (from reference)
#define MM 5000      // matches
#define LC 4800      // coarse cells
// feat_f: [4][128][240][320], feat_c: [4][4800][256]

typedef __attribute__((ext_vector_type(8))) short bf16x8;
typedef __attribute__((ext_vector_type(4))) float f32x4;

__device__ __forceinline__ unsigned short f2bf(float f) {
    unsigned int u = __builtin_bit_cast(unsigned int, f);
    u += 0x7fffu + ((u >> 16) & 1u);   // RNE
    return (unsigned short)(u >> 16);
}

// K0: Wcomb = merge_w[:,128:] @ down_proj_w  -> bf16 [128][256]
//     W1    = merge_w[:,:128]                -> bf16 [128][128]
//     bvec  = merge_b + down_proj_b @ merge_w[:,128:].T   (fp32 [128])
__global__ void k0_prep(const float* __restrict__ merge_w,
                        const float* __restrict__ down_w,
                        const float* __restrict__ merge_b,
                        const float* __restrict__ down_b,
                        unsigned short* __restrict__ w1_bf,
                        unsigned short* __restrict__ wc_bf,
                        float* __restrict__ bvec)
{
    int o = blockIdx.x * 256 + threadIdx.x;        // 128 blocks -> o in [0,32768)
    int cf = o >> 8, cc = o & 255;
    const float* w2row = merge_w + cf * 256 + 128; // W2[cf][:]
    float acc = 0.f;
    #pragma unroll 4
    for (int j = 0; j < 128; ++j)
        acc = fmaf(w2row[j], down_w[j * 256 + cc], acc);
    wc_bf[o] = f2bf(acc);
    if (o < 16384)
        w1_bf[o] = f2bf(merge_w[(o >> 7) * 256 + (o & 127)]);
    if (o < 128) {
        const float* w2r = merge_w + o * 256 + 128;
        float a = merge_b[o];
        for (int j = 0; j < 128; ++j) a = fmaf(down_b[j], w2r[j], a);
        bvec[o] = a;
    }
}

// K1: bias2[sm][cf] = feat_c_row(sm) @ Wcomb[cf][:] + bvec[cf]; sm in [0,10000)
// block = 32 sm rows x 128 cf, K=256, bf16 MFMA 16x16x32
__global__ void __launch_bounds__(256) k1_bias(
    const float* __restrict__ feat_c0, const float* __restrict__ feat_c1,
    const int* __restrict__ b_ids, const int* __restrict__ i_ids,
    const int* __restrict__ j_ids,
    const unsigned short* __restrict__ wc_bf, const float* __restrict__ bvec,
    float* __restrict__ bias2)
{
    __shared__ unsigned short ac[32][264];   // 256 + 8 pad (bank shift)
    const int t = threadIdx.x;
    const int base = blockIdx.x * 32;
    {
        int row = t >> 3;
        int seg = (t & 7) * 32;
        int sm = base + row; if (sm > 2 * MM - 1) sm = 2 * MM - 1;
        int side = sm >= MM;
        int mm = sm - side * MM;
        int id = side ? j_ids[mm] : i_ids[mm];
        int b  = b_ids[mm];
        const float* src = (side ? feat_c1 : feat_c0)
                           + (size_t)(b * LC + id) * 256 + seg;
        const float4* s4 = (const float4*)src;
        #pragma unroll
        for (int i = 0; i < 8; ++i) {
            float4 v = s4[i];
            ushort4 u; u.x = f2bf(v.x); u.y = f2bf(v.y); u.z = f2bf(v.z); u.w = f2bf(v.w);
            *(ushort4*)&ac[row][seg + i * 4] = u;
        }
    }
    __syncthreads();
    const int lane = t & 63, wave = t >> 6;
    const int ln = lane & 15, q = lane >> 4;
    const int n0 = wave * 32;
    f32x4 acc[2][2] = {};
    #pragma unroll
    for (int k0 = 0; k0 < 8; ++k0) {
        bf16x8 a0 = *(const bf16x8*)&ac[ln][k0 * 32 + q * 8];
        bf16x8 a1 = *(const bf16x8*)&ac[16 + ln][k0 * 32 + q * 8];
        bf16x8 b0 = *(const bf16x8*)(wc_bf + (size_t)(n0 + ln) * 256 + k0 * 32 + q * 8);
        bf16x8 b1 = *(const bf16x8*)(wc_bf + (size_t)(n0 + 16 + ln) * 256 + k0 * 32 + q * 8);
        acc[0][0] = __builtin_amdgcn_mfma_f32_16x16x32_bf16(a0, b0, acc[0][0], 0, 0, 0);
        acc[0][1] = __builtin_amdgcn_mfma_f32_16x16x32_bf16(a0, b1, acc[0][1], 0, 0, 0);
        acc[1][0] = __builtin_amdgcn_mfma_f32_16x16x32_bf16(a1, b0, acc[1][0], 0, 0, 0);
        acc[1][1] = __builtin_amdgcn_mfma_f32_16x16x32_bf16(a1, b1, acc[1][1], 0, 0, 0);
    }
    #pragma unroll
    for (int mt = 0; mt < 2; ++mt)
      #pragma unroll
      for (int nt = 0; nt < 2; ++nt) {
        int cf = n0 + nt * 16 + ln;
        float bv = bvec[cf];
        #pragma unroll
        for (int r = 0; r < 4; ++r) {
            int sm = base + mt * 16 + q * 4 + r;
            if (sm < 2 * MM)
                bias2[(size_t)sm * 128 + cf] = acc[mt][nt][r] + bv;
        }
      }
}

// K2: per match-side: gather scrambled-view window [25][128] -> LDS bf16,
// D = fw @ W1^T + bias2 row, store [25][128] fp32.
// W1 B-fragments live in REGISTERS (32 VGPR/lane), loaded from global
// (32 KB array -> L1/L2 resident). LDS = fw only (~9 KB) -> high occupancy.
__global__ void __launch_bounds__(256, 5) k2_main(
    const float* __restrict__ feat_f0, const float* __restrict__ feat_f1,
    const int* __restrict__ b_ids, const int* __restrict__ i_ids,
    const int* __restrict__ j_ids,
    const unsigned short* __restrict__ w1_bf, const float* __restrict__ bias2,
    float* __restrict__ out)
{
    __shared__ unsigned short fw[32][136];    // 25 used rows; +8 pad
    __shared__ float brow[128];
    const int t = threadIdx.x;
    const int bx = blockIdx.x;                 // [0,10000)
    const int side = bx >= MM;
    const int m = bx - side * MM;
    const float* feat = side ? feat_f1 : feat_f0;
    const int l = side ? j_ids[m] : i_ids[m];
    const int n = b_ids[m];

    const int lane = t & 63, wave = t >> 6;
    const int ln = lane & 15, q = lane >> 4;
    const int n0 = wave * 32;

    // W1 B-fragments: bf[nt][k0] -> rows (n0+nt*16+ln), k-slice k0*32+q*8
    bf16x8 bf[2][4];
    #pragma unroll
    for (int nt = 0; nt < 2; ++nt)
      #pragma unroll
      for (int k0 = 0; k0 < 4; ++k0)
        bf[nt][k0] = *(const bf16x8*)(w1_bf + (n0 + nt * 16 + ln) * 128 + k0 * 32 + q * 8);

    if (t < 128) brow[t] = bias2[(size_t)bx * 128 + t];

    // gather: view element (l, w, c) = unfold flat l*3200 + w*128 + c
    const int fbase = l * 3200;
    const float* fn = feat + (size_t)n * (128 * 240 * 320);
    #pragma unroll
    for (int it = 0; it < 13; ++it) {
        int idx = t + it * 256;
        if (idx < 3200) {
            int F  = fbase + idx;
            int cc = F / 4800;  int p  = F - cc * 4800;
            int ch = cc / 25;   int k5 = cc - ch * 25;
            int kh = k5 / 5;    int kw = k5 - kh * 5;
            int ho = p / 80;    int wo = p - ho * 80;
            int r   = 4 * ho + kh - 2;      // always < 240
            int col = 4 * wo + kw - 2;      // always < 320
            float v = 0.f;
            if (r >= 0 && col >= 0)
                v = fn[(ch * 240 + r) * 320 + col];
            fw[idx >> 7][idx & 127] = f2bf(v);
        }
    }
    __syncthreads();

    f32x4 acc[2][2] = {};
    #pragma unroll
    for (int k0 = 0; k0 < 4; ++k0) {
        bf16x8 a0 = *(const bf16x8*)&fw[ln][k0 * 32 + q * 8];
        bf16x8 a1 = *(const bf16x8*)&fw[16 + ln][k0 * 32 + q * 8];   // rows>=25 garbage: only feeds D rows>=25 (unstored)
        acc[0][0] = __builtin_amdgcn_mfma_f32_16x16x32_bf16(a0, bf[0][k0], acc[0][0], 0, 0, 0);
        acc[0][1] = __builtin_amdgcn_mfma_f32_16x16x32_bf16(a0, bf[1][k0], acc[0][1], 0, 0, 0);
        acc[1][0] = __builtin_amdgcn_mfma_f32_16x16x32_bf16(a1, bf[0][k0], acc[1][0], 0, 0, 0);
        acc[1][1] = __builtin_amdgcn_mfma_f32_16x16x32_bf16(a1, bf[1][k0], acc[1][1], 0, 0, 0);
    }
    float* ob = out + (size_t)bx * 3200;
    #pragma unroll
    for (int nt = 0; nt < 2; ++nt) {
        int cf = n0 + nt * 16 + ln;
        float bv = brow[cf];
        #pragma unroll
        for (int mt = 0; mt < 2; ++mt)
          #pragma unroll
          for (int r = 0; r < 4; ++r) {
            int w = mt * 16 + q * 4 + r;
            if (w < 25)
                ob[w * 128 + cf] = acc[mt][nt][r] + bv;
          }
    }
}

extern "C" void kernel_launch(void* const* d_in, const int* in_sizes, int n_in,
                              void* d_out, int out_size, void* d_ws, size_t ws_size,
                              hipStream_t stream) {
    const float* feat_f0 = (const float*)d_in[0];
    const float* feat_f1 = (const float*)d_in[1];
    const float* feat_c0 = (const float*)d_in[2];
    const float* feat_c1 = (const float*)d_in[3];
    const int*   b_ids   = (const int*)d_in[4];
    const int*   i_ids   = (const int*)d_in[5];
    const int*   j_ids   = (const int*)d_in[6];
    const float* down_w  = (const float*)d_in[7];
    const float* down_b  = (const float*)d_in[8];
    const float* merge_w = (const float*)d_in[9];
    const float* merge_b = (const float*)d_in[10];
    float* out = (float*)d_out;

    char* ws = (char*)d_ws;
    unsigned short* w1_bf = (unsigned short*)(ws);            // 32 KB
    unsigned short* wc_bf = (unsigned short*)(ws + 32768);    // 64 KB
    float* bvec  = (float*)(ws + 98304);                      // 512 B
    float* bias2 = (float*)(ws + 98816);                      // 10000*128*4 = 5.12 MB

    hipLaunchKernelGGL(k0_prep, dim3(128), dim3(256), 0, stream,
                       merge_w, down_w, merge_b, down_b, w1_bf, wc_bf, bvec);
    hipLaunchKernelGGL(k1_bias, dim3((2 * MM + 31) / 32), dim3(256), 0, stream,
                       feat_c0, feat_c1, b_ids, i_ids, j_ids, wc_bf, bvec, bias2);
    hipLaunchKernelGGL(k2_main, dim3(2 * MM), dim3(256), 0, stream,
                       feat_f0, feat_f1, b_ids, i_ids, j_ids, w1_bf, bias2, out);
}